// Round 4
// baseline (331.862 us; speedup 1.0000x reference)
//
#include <hip/hip_runtime.h>

#define BB    8
#define CC    64
#define NN    2048
#define GG    2048
#define MFREQ 4032

typedef __attribute__((ext_vector_type(4))) float f32x4;
typedef __attribute__((ext_vector_type(8))) short bf16x8;

static __device__ __forceinline__ unsigned short f2bf(float f) {
    union { float f; unsigned u; } v; v.f = f;
    unsigned r = v.u + 0x7fff + ((v.u >> 16) & 1);   // RNE
    return (unsigned short)(r >> 16);
}

#define ASYNC_COPY16(gp, lp)                                                        \
    __builtin_amdgcn_global_load_lds(                                               \
        (const __attribute__((address_space(1))) unsigned int*)(gp),                \
        (__attribute__((address_space(3))) unsigned int*)(lp), 16, 0, 0)

// ---------------------------------------------------------------------------
// Fused streaming packs (all are float4 -> bf16x4 with index remap):
//  blocks [0, 8192)        : Af [4096 x 2048]  rows 0..2047 = Vf_re[f(g)], rows 2048.. = Vf_im
//  blocks [8192, 9216)     : Xb [512 x 2048]   bf16 cast of x
//  blocks [9216, 25600)    : Mi [2048 x 8192]  Hermitian-folded inverse basis
__global__ __launch_bounds__(256) void pack_all(const float* __restrict__ vf_re,
                                                const float* __restrict__ vf_im,
                                                const float* __restrict__ x,
                                                const float* __restrict__ vi_re,
                                                const float* __restrict__ vi_im,
                                                unsigned short* __restrict__ af,
                                                unsigned short* __restrict__ xb,
                                                unsigned short* __restrict__ mi) {
    int blk = blockIdx.x;
    float4 v;
    unsigned short* dst;
    if (blk < 8192) {
        int idx = blk * 256 + threadIdx.x;
        int m = idx >> 9;
        int q = (idx & 511) * 4;
        int g = m & 2047;
        int f = (g >> 5) * 63 + (g & 31);
        const float* src = (m < 2048 ? vf_re : vf_im) + (size_t)f * 2048 + q;
        v = *(const float4*)src;
        dst = af + (size_t)m * 2048 + q;
    } else if (blk < 9216) {
        int idx = (blk - 8192) * 256 + threadIdx.x;
        int q = idx * 4;
        v = *(const float4*)(x + q);
        dst = xb + q;
    } else {
        int idx = (blk - 9216) * 256 + threadIdx.x;
        int n = idx >> 11;
        int q4 = (idx & 2047) * 4;
        int region = q4 >> 11;
        int off = q4 & 2047;
        if (region == 0) {
            v = *(const float4*)(vi_re + (size_t)n * MFREQ + off);
        } else if (region == 1) {
            float4 t = *(const float4*)(vi_im + (size_t)n * MFREQ + off);
            v.x = -t.x; v.y = -t.y; v.z = -t.z; v.w = -t.w;
        } else {
            if (off < 64) { v.x = v.y = v.z = v.w = 0.0f; }
            else {
                const float* src = (region == 2 ? vi_re : vi_im);
                float4 t = *(const float4*)(src + (size_t)n * MFREQ + (4092 - off));
                v.x = t.w; v.y = t.z; v.z = t.y; v.w = t.x;
            }
        }
        dst = mi + (size_t)n * 8192 + q4;
    }
    ushort4 o; o.x = f2bf(v.x); o.y = f2bf(v.y); o.z = f2bf(v.z); o.w = f2bf(v.w);
    *(ushort4*)dst = o;
}

// Transpose weights: wt[g][io] = packed bf16 (re | im<<16)
__global__ __launch_bounds__(256) void pack_wt(const float* __restrict__ w1_re,
                                               const float* __restrict__ w1_im,
                                               const float* __restrict__ w2_re,
                                               const float* __restrict__ w2_im,
                                               unsigned int* __restrict__ wt) {
    __shared__ float sre[64][65];
    __shared__ float sim[64][65];
    int wsel = blockIdx.z;
    const float* wre = wsel ? w2_re : w1_re;
    const float* wim = wsel ? w2_im : w1_im;
    int io0 = blockIdx.y * 64, xy0 = blockIdx.x * 64;
    int t = threadIdx.x;
    int r = t >> 2, cq = (t & 3) * 16;
    for (int j = 0; j < 16; j += 4) {
        float4 a = *(const float4*)(wre + (size_t)(io0 + r) * 1024 + xy0 + cq + j);
        float4 b = *(const float4*)(wim + (size_t)(io0 + r) * 1024 + xy0 + cq + j);
        sre[r][cq + j + 0] = a.x; sre[r][cq + j + 1] = a.y; sre[r][cq + j + 2] = a.z; sre[r][cq + j + 3] = a.w;
        sim[r][cq + j + 0] = b.x; sim[r][cq + j + 1] = b.y; sim[r][cq + j + 2] = b.z; sim[r][cq + j + 3] = b.w;
    }
    __syncthreads();
    int iol = t & 63, gq = t >> 6;
    for (int jj = 0; jj < 16; ++jj) {
        int gl = jj * 4 + gq;
        int g = xy0 + gl + wsel * 1024;
        unsigned int o = (unsigned int)f2bf(sre[iol][gl]) | ((unsigned int)f2bf(sim[iol][gl]) << 16);
        wt[(size_t)g * 4096 + io0 + iol] = o;
    }
}

// phi[b][g] = sum_e m{1,2}[xy][e] * emb[b][e]
__global__ __launch_bounds__(256) void phi_k(const float* __restrict__ m1_re,
                                             const float* __restrict__ m1_im,
                                             const float* __restrict__ m2_re,
                                             const float* __restrict__ m2_im,
                                             const float* __restrict__ emb,
                                             float* __restrict__ phi_re,
                                             float* __restrict__ phi_im) {
    int g = blockIdx.x, b = blockIdx.y, e = threadIdx.x;
    int xy = g & 1023;
    const float* mr = (g < 1024 ? m1_re : m2_re) + xy * 256;
    const float* mi = (g < 1024 ? m1_im : m2_im) + xy * 256;
    float em = emb[b * 256 + e];
    float pr = mr[e] * em, pi = mi[e] * em;
    __shared__ float sr[4], si[4];
    for (int s = 32; s > 0; s >>= 1) { pr += __shfl_down(pr, s); pi += __shfl_down(pi, s); }
    int wid = e >> 6;
    if ((e & 63) == 0) { sr[wid] = pr; si[wid] = pi; }
    __syncthreads();
    if (e == 0) {
        phi_re[b * 2048 + g] = sr[0] + sr[1] + sr[2] + sr[3];
        phi_im[b * 2048 + g] = si[0] + si[1] + si[2] + si[3];
    }
}

// ---------------------------------------------------------------------------
// Split-K MFMA GEMM: P[z][M][N] = A[M][K-slice] @ B[N][K-slice]^T
// 128x128 tile, BK=64, global_load_lds(16B) staging, XOR-swizzled source fetch.
__global__ __launch_bounds__(256, 2) void gemm_sk(const unsigned short* __restrict__ A,
                                                  const unsigned short* __restrict__ Bm,
                                                  float* __restrict__ P,
                                                  int M, int N, int K, int Kper) {
    __shared__ unsigned short As[128 * 64];
    __shared__ unsigned short Bs[128 * 64];
    int t = threadIdx.x;
    int lane = t & 63, w = t >> 6;
    int m0 = blockIdx.y * 128, n0 = blockIdx.x * 128;
    int z = blockIdx.z;
    int kbase = z * Kper;
    int wm = (w >> 1) * 64, wn = (w & 1) * 64;
    int lr = lane & 15, quad = lane >> 4;
    int rsub = lane >> 3, slot = lane & 7;

    f32x4 acc[4][4] = {};

    for (int kk = kbase; kk < kbase + Kper; kk += 64) {
        __syncthreads();
        #pragma unroll
        for (int l = 0; l < 4; ++l) {
            int r = (w * 4 + l) * 8 + rsub;
            int c = slot ^ (r & 7);
            ASYNC_COPY16(A + (size_t)(m0 + r) * K + kk + c * 8, As + r * 64 + slot * 8);
            ASYNC_COPY16(Bm + (size_t)(n0 + r) * K + kk + c * 8, Bs + r * 64 + slot * 8);
        }
        __syncthreads();
        #pragma unroll
        for (int ks = 0; ks < 2; ++ks) {
            bf16x8 af[4], bfr[4];
            #pragma unroll
            for (int i = 0; i < 4; ++i) {
                int row = wm + i * 16 + lr;
                int q = (ks * 4 + quad) ^ (row & 7);
                af[i] = *(const bf16x8*)(As + row * 64 + q * 8);
                int rowb = wn + i * 16 + lr;
                int qb = (ks * 4 + quad) ^ (rowb & 7);
                bfr[i] = *(const bf16x8*)(Bs + rowb * 64 + qb * 8);
            }
            #pragma unroll
            for (int i = 0; i < 4; ++i)
            #pragma unroll
            for (int j = 0; j < 4; ++j)
                acc[i][j] = __builtin_amdgcn_mfma_f32_16x16x32_bf16(af[i], bfr[j], acc[i][j], 0, 0, 0);
        }
    }
    float* Pz = P + (size_t)z * M * N;
    #pragma unroll
    for (int i = 0; i < 4; ++i)
    #pragma unroll
    for (int j = 0; j < 4; ++j) {
        int rr = m0 + wm + i * 16 + quad * 4;
        int cc = n0 + wn + j * 16 + lr;
        float* cp = Pz + (size_t)rr * N + cc;
        f32x4 v = acc[i][j];
        cp[0]             = v.x;
        cp[(size_t)N]     = v.y;
        cp[2 * (size_t)N] = v.z;
        cp[3 * (size_t)N] = v.w;
    }
}

// Sum split-K partials: out[i] = alpha * sum_z P[z][i]
__global__ __launch_bounds__(256) void reduce_k(const float* __restrict__ P,
                                                float* __restrict__ out,
                                                int S, size_t elems, float alpha) {
    size_t idx = ((size_t)blockIdx.x * 256 + threadIdx.x) * 4;
    float4 s = *(const float4*)(P + idx);
    for (int zz = 1; zz < S; ++zz) {
        float4 v = *(const float4*)(P + (size_t)zz * elems + idx);
        s.x += v.x; s.y += v.y; s.z += v.z; s.w += v.w;
    }
    s.x *= alpha; s.y *= alpha; s.z *= alpha; s.w *= alpha;
    *(float4*)(out + idx) = s;
}

// ---------------------------------------------------------------------------
// Middle: g-tile of 8 per block (grid 256). Per g: stage Wt row (16KB = 4x
// 256thr x 16B async) + O1 row (4KB = 1x) via global_load_lds; each thread
// (b,oo) computes 2 complex outputs; results held in VGPRs as packed bf16 and
// written as uint4 (8 modes x 2B) rows - coalescable 16B stores.
__global__ __launch_bounds__(256) void middle_k(const float* __restrict__ O1,
                                                const unsigned int* __restrict__ wt,
                                                const float* __restrict__ phi_re,
                                                const float* __restrict__ phi_im,
                                                unsigned short* __restrict__ Yt) {
    __shared__ unsigned int sW[4096];     // 16 KB: Wt row for current g
    __shared__ float sInc[1024];          // re[512] | im[512]
    int t = threadIdx.x;
    int g0 = blockIdx.x * 8;
    int b = t >> 5, oo = t & 31;

    unsigned short re0[8], im0[8], re1[8], im1[8];

    #pragma unroll
    for (int gt = 0; gt < 8; ++gt) {
        int g = g0 + gt;
        __syncthreads();
        // stage Wt row: 4 x (256 threads x 16B) = 16 KB  [R3 bug: was 1x = 4KB]
        #pragma unroll
        for (int j = 0; j < 4; ++j)
            ASYNC_COPY16(wt + (size_t)g * 4096 + (j * 256 + t) * 4, sW + (j * 256 + t) * 4);
        // stage O1 re/im rows: waves 0-1 -> re, waves 2-3 -> im (4 KB total)
        {
            const float* src = (t < 128) ? (O1 + (size_t)g * 512 + t * 4)
                                         : (O1 + (size_t)(2048 + g) * 512 + (t - 128) * 4);
            ASYNC_COPY16(src, sInc + t * 4);
        }
        __syncthreads();

        float ar0 = 0.f, ai0 = 0.f, ar1 = 0.f, ai1 = 0.f;
        #pragma unroll 8
        for (int i = 0; i < 64; ++i) {
            float ax = sInc[b * 64 + i];
            float ay = sInc[512 + b * 64 + i];
            unsigned int u0 = sW[i * 64 + oo];
            unsigned int u1 = sW[i * 64 + oo + 32];
            float w0r = __uint_as_float(u0 << 16);
            float w0i = __uint_as_float(u0 & 0xffff0000u);
            float w1r = __uint_as_float(u1 << 16);
            float w1i = __uint_as_float(u1 & 0xffff0000u);
            ar0 += ax * w0r - ay * w0i;  ai0 += ax * w0i + ay * w0r;
            ar1 += ax * w1r - ay * w1i;  ai1 += ax * w1i + ay * w1r;
        }
        float pr = phi_re[b * 2048 + g], pi = phi_im[b * 2048 + g];
        re0[gt] = f2bf(pr * ar0 - pi * ai0);
        im0[gt] = f2bf(pr * ai0 + pi * ar0);
        re1[gt] = f2bf(pr * ar1 - pi * ai1);
        im1[gt] = f2bf(pr * ai1 + pi * ar1);
    }

    uint4 vre0, vim0, vre1, vim1;
    vre0.x = re0[0] | (re0[1] << 16); vre0.y = re0[2] | (re0[3] << 16);
    vre0.z = re0[4] | (re0[5] << 16); vre0.w = re0[6] | (re0[7] << 16);
    vim0.x = im0[0] | (im0[1] << 16); vim0.y = im0[2] | (im0[3] << 16);
    vim0.z = im0[4] | (im0[5] << 16); vim0.w = im0[6] | (im0[7] << 16);
    vre1.x = re1[0] | (re1[1] << 16); vre1.y = re1[2] | (re1[3] << 16);
    vre1.z = re1[4] | (re1[5] << 16); vre1.w = re1[6] | (re1[7] << 16);
    vim1.x = im1[0] | (im1[1] << 16); vim1.y = im1[2] | (im1[3] << 16);
    vim1.z = im1[4] | (im1[5] << 16); vim1.w = im1[6] | (im1[7] << 16);

    {
        size_t r0 = (size_t)(b * 64 + oo) * 8192;
        size_t rf = (size_t)(b * 64 + 63 - oo) * 8192;
        *(uint4*)(Yt + r0 + g0)        = vre0;
        *(uint4*)(Yt + r0 + 2048 + g0) = vim0;
        *(uint4*)(Yt + rf + 4096 + g0) = vre0;
        *(uint4*)(Yt + rf + 6144 + g0) = vim0;
    }
    {
        int o = oo + 32;
        size_t r0 = (size_t)(b * 64 + o) * 8192;
        size_t rf = (size_t)(b * 64 + 63 - o) * 8192;
        *(uint4*)(Yt + r0 + g0)        = vre1;
        *(uint4*)(Yt + r0 + 2048 + g0) = vim1;
        *(uint4*)(Yt + rf + 4096 + g0) = vre1;
        *(uint4*)(Yt + rf + 6144 + g0) = vim1;
    }
}

// ---------------------------------------------------------------------------
extern "C" void kernel_launch(void* const* d_in, const int* in_sizes, int n_in,
                              void* d_out, int out_size, void* d_ws, size_t ws_size,
                              hipStream_t stream) {
    const float* x     = (const float*)d_in[0];
    const float* emb   = (const float*)d_in[1];
    const float* vf_re = (const float*)d_in[2];
    const float* vf_im = (const float*)d_in[3];
    const float* vi_re = (const float*)d_in[4];
    const float* vi_im = (const float*)d_in[5];
    const float* w1_re = (const float*)d_in[6];
    const float* w1_im = (const float*)d_in[7];
    const float* w2_re = (const float*)d_in[8];
    const float* w2_im = (const float*)d_in[9];
    const float* m1_re = (const float*)d_in[10];
    const float* m1_im = (const float*)d_in[11];
    const float* m2_re = (const float*)d_in[12];
    const float* m2_im = (const float*)d_in[13];

    char* ws = (char*)d_ws;
    unsigned short* Af = (unsigned short*)(ws);                 // 16,777,216
    unsigned short* Xb = (unsigned short*)(ws + 16777216);      //  2,097,152
    unsigned short* Mi = (unsigned short*)(ws + 18874368);      // 33,554,432
    unsigned int*   Wt = (unsigned int*)(ws + 52428800);        // 33,554,432 (bf16 pairs)
    float*          O1 = (float*)(ws + 85983232);               //  8,388,608
    float*       PhiRe = (float*)(ws + 94371840);               //     65,536
    float*       PhiIm = (float*)(ws + 94437376);               //     65,536
    unsigned short* Yt = (unsigned short*)(ws + 94502912);      //  8,388,608
    float*          P  = (float*)(ws + 102891520);              // 33,554,432 partials -> 136,445,952
    float* out = (float*)d_out;

    pack_all<<<25600, 256, 0, stream>>>(vf_re, vf_im, x, vi_re, vi_im, Af, Xb, Mi);
    pack_wt<<<dim3(16, 64, 2), 256, 0, stream>>>(w1_re, w1_im, w2_re, w2_im, Wt);
    phi_k<<<dim3(2048, 8), 256, 0, stream>>>(m1_re, m1_im, m2_re, m2_im, emb, PhiRe, PhiIm);

    // Forward: O1[4096][512] = Af[4096x2048] @ Xb[512x2048]^T, split-K 4
    gemm_sk<<<dim3(4, 32, 4), 256, 0, stream>>>(Af, Xb, P, 4096, 512, 2048, 512);
    reduce_k<<<2048, 256, 0, stream>>>(P, O1, 4, (size_t)4096 * 512, 1.0f);

    middle_k<<<256, 256, 0, stream>>>(O1, Wt, PhiRe, PhiIm, Yt);

    // Inverse: out[512][2048] = (2/N) * Yt[512x8192] @ Mi[2048x8192]^T, split-K 8
    gemm_sk<<<dim3(16, 4, 8), 256, 0, stream>>>(Yt, Mi, P, 512, 2048, 8192, 1024);
    reduce_k<<<1024, 256, 0, stream>>>(P, out, 8, (size_t)512 * 2048, 1.0f / 1024.0f);
}

// Round 5
// 319.226 us; speedup vs baseline: 1.0396x; 1.0396x over previous
//
#include <hip/hip_runtime.h>

#define BB    8
#define CC    64
#define NN    2048
#define GG    2048
#define MFREQ 4032

typedef __attribute__((ext_vector_type(4))) float f32x4;
typedef __attribute__((ext_vector_type(8))) short bf16x8;

static __device__ __forceinline__ unsigned short f2bf(float f) {
    union { float f; unsigned u; } v; v.f = f;
    unsigned r = v.u + 0x7fff + ((v.u >> 16) & 1);   // RNE
    return (unsigned short)(r >> 16);
}

#define ASYNC_COPY16(gp, lp)                                                        \
    __builtin_amdgcn_global_load_lds(                                               \
        (const __attribute__((address_space(1))) unsigned int*)(gp),                \
        (__attribute__((address_space(3))) unsigned int*)(lp), 16, 0, 0)

// ---------------------------------------------------------------------------
// Fused streaming packs:
//  blocks [0, 8192)    : Af [4096 x 2048]
//  blocks [8192, 9216) : Xb [512 x 2048]
//  blocks [9216, 25600): Mi [2048 x 8192]
__global__ __launch_bounds__(256) void pack_all(const float* __restrict__ vf_re,
                                                const float* __restrict__ vf_im,
                                                const float* __restrict__ x,
                                                const float* __restrict__ vi_re,
                                                const float* __restrict__ vi_im,
                                                unsigned short* __restrict__ af,
                                                unsigned short* __restrict__ xb,
                                                unsigned short* __restrict__ mi) {
    int blk = blockIdx.x;
    float4 v;
    unsigned short* dst;
    if (blk < 8192) {
        int idx = blk * 256 + threadIdx.x;
        int m = idx >> 9;
        int q = (idx & 511) * 4;
        int g = m & 2047;
        int f = (g >> 5) * 63 + (g & 31);
        const float* src = (m < 2048 ? vf_re : vf_im) + (size_t)f * 2048 + q;
        v = *(const float4*)src;
        dst = af + (size_t)m * 2048 + q;
    } else if (blk < 9216) {
        int idx = (blk - 8192) * 256 + threadIdx.x;
        int q = idx * 4;
        v = *(const float4*)(x + q);
        dst = xb + q;
    } else {
        int idx = (blk - 9216) * 256 + threadIdx.x;
        int n = idx >> 11;
        int q4 = (idx & 2047) * 4;
        int region = q4 >> 11;
        int off = q4 & 2047;
        if (region == 0) {
            v = *(const float4*)(vi_re + (size_t)n * MFREQ + off);
        } else if (region == 1) {
            float4 t = *(const float4*)(vi_im + (size_t)n * MFREQ + off);
            v.x = -t.x; v.y = -t.y; v.z = -t.z; v.w = -t.w;
        } else {
            if (off < 64) { v.x = v.y = v.z = v.w = 0.0f; }
            else {
                const float* src = (region == 2 ? vi_re : vi_im);
                float4 t = *(const float4*)(src + (size_t)n * MFREQ + (4092 - off));
                v.x = t.w; v.y = t.z; v.z = t.y; v.w = t.x;
            }
        }
        dst = mi + (size_t)n * 8192 + q4;
    }
    ushort4 o; o.x = f2bf(v.x); o.y = f2bf(v.y); o.z = f2bf(v.z); o.w = f2bf(v.w);
    *(ushort4*)dst = o;
}

// Transpose weights: wt[g][io] = packed bf16 (re | im<<16)
__global__ __launch_bounds__(256) void pack_wt(const float* __restrict__ w1_re,
                                               const float* __restrict__ w1_im,
                                               const float* __restrict__ w2_re,
                                               const float* __restrict__ w2_im,
                                               unsigned int* __restrict__ wt) {
    __shared__ float sre[64][65];
    __shared__ float sim[64][65];
    int wsel = blockIdx.z;
    const float* wre = wsel ? w2_re : w1_re;
    const float* wim = wsel ? w2_im : w1_im;
    int io0 = blockIdx.y * 64, xy0 = blockIdx.x * 64;
    int t = threadIdx.x;
    int r = t >> 2, cq = (t & 3) * 16;
    for (int j = 0; j < 16; j += 4) {
        float4 a = *(const float4*)(wre + (size_t)(io0 + r) * 1024 + xy0 + cq + j);
        float4 b = *(const float4*)(wim + (size_t)(io0 + r) * 1024 + xy0 + cq + j);
        sre[r][cq + j + 0] = a.x; sre[r][cq + j + 1] = a.y; sre[r][cq + j + 2] = a.z; sre[r][cq + j + 3] = a.w;
        sim[r][cq + j + 0] = b.x; sim[r][cq + j + 1] = b.y; sim[r][cq + j + 2] = b.z; sim[r][cq + j + 3] = b.w;
    }
    __syncthreads();
    int iol = t & 63, gq = t >> 6;
    for (int jj = 0; jj < 16; ++jj) {
        int gl = jj * 4 + gq;
        int g = xy0 + gl + wsel * 1024;
        unsigned int o = (unsigned int)f2bf(sre[iol][gl]) | ((unsigned int)f2bf(sim[iol][gl]) << 16);
        wt[(size_t)g * 4096 + io0 + iol] = o;
    }
}

// phi[b][g] = sum_e m{1,2}[xy][e] * emb[b][e]
__global__ __launch_bounds__(256) void phi_k(const float* __restrict__ m1_re,
                                             const float* __restrict__ m1_im,
                                             const float* __restrict__ m2_re,
                                             const float* __restrict__ m2_im,
                                             const float* __restrict__ emb,
                                             float* __restrict__ phi_re,
                                             float* __restrict__ phi_im) {
    int g = blockIdx.x, b = blockIdx.y, e = threadIdx.x;
    int xy = g & 1023;
    const float* mr = (g < 1024 ? m1_re : m2_re) + xy * 256;
    const float* mi = (g < 1024 ? m1_im : m2_im) + xy * 256;
    float em = emb[b * 256 + e];
    float pr = mr[e] * em, pi = mi[e] * em;
    __shared__ float sr[4], si[4];
    for (int s = 32; s > 0; s >>= 1) { pr += __shfl_down(pr, s); pi += __shfl_down(pi, s); }
    int wid = e >> 6;
    if ((e & 63) == 0) { sr[wid] = pr; si[wid] = pi; }
    __syncthreads();
    if (e == 0) {
        phi_re[b * 2048 + g] = sr[0] + sr[1] + sr[2] + sr[3];
        phi_im[b * 2048 + g] = si[0] + si[1] + si[2] + si[3];
    }
}

// ---------------------------------------------------------------------------
// Split-K MFMA GEMM: P[z] = A[M][Kslice] @ B[N][Kslice]^T
// ilv=1 (forward only): store element (rr,cc) at ((rr&2047)*1024 + cc*2 + (rr>>11))
// i.e. O1 interleaved as [g][c][{re,im}] so middle can ds_read_b64 float2.
__global__ __launch_bounds__(256, 2) void gemm_sk(const unsigned short* __restrict__ A,
                                                  const unsigned short* __restrict__ Bm,
                                                  float* __restrict__ P,
                                                  int M, int N, int K, int Kper, int ilv) {
    __shared__ unsigned short As[128 * 64];
    __shared__ unsigned short Bs[128 * 64];
    int t = threadIdx.x;
    int lane = t & 63, w = t >> 6;
    int m0 = blockIdx.y * 128, n0 = blockIdx.x * 128;
    int z = blockIdx.z;
    int kbase = z * Kper;
    int wm = (w >> 1) * 64, wn = (w & 1) * 64;
    int lr = lane & 15, quad = lane >> 4;
    int rsub = lane >> 3, slot = lane & 7;

    f32x4 acc[4][4] = {};

    for (int kk = kbase; kk < kbase + Kper; kk += 64) {
        __syncthreads();
        #pragma unroll
        for (int l = 0; l < 4; ++l) {
            int r = (w * 4 + l) * 8 + rsub;
            int c = slot ^ (r & 7);
            ASYNC_COPY16(A + (size_t)(m0 + r) * K + kk + c * 8, As + r * 64 + slot * 8);
            ASYNC_COPY16(Bm + (size_t)(n0 + r) * K + kk + c * 8, Bs + r * 64 + slot * 8);
        }
        __syncthreads();
        #pragma unroll
        for (int ks = 0; ks < 2; ++ks) {
            bf16x8 af[4], bfr[4];
            #pragma unroll
            for (int i = 0; i < 4; ++i) {
                int row = wm + i * 16 + lr;
                int q = (ks * 4 + quad) ^ (row & 7);
                af[i] = *(const bf16x8*)(As + row * 64 + q * 8);
                int rowb = wn + i * 16 + lr;
                int qb = (ks * 4 + quad) ^ (rowb & 7);
                bfr[i] = *(const bf16x8*)(Bs + rowb * 64 + qb * 8);
            }
            #pragma unroll
            for (int i = 0; i < 4; ++i)
            #pragma unroll
            for (int j = 0; j < 4; ++j)
                acc[i][j] = __builtin_amdgcn_mfma_f32_16x16x32_bf16(af[i], bfr[j], acc[i][j], 0, 0, 0);
        }
    }
    float* Pz = P + (size_t)z * M * N;
    size_t rstride = ilv ? 1024 : (size_t)N;
    #pragma unroll
    for (int i = 0; i < 4; ++i)
    #pragma unroll
    for (int j = 0; j < 4; ++j) {
        int rr = m0 + wm + i * 16 + quad * 4;
        int cc = n0 + wn + j * 16 + lr;
        size_t base = ilv ? ((size_t)(rr & 2047) * 1024 + cc * 2 + (rr >> 11))
                          : ((size_t)rr * N + cc);
        float* cp = Pz + base;
        f32x4 v = acc[i][j];
        cp[0]           = v.x;
        cp[rstride]     = v.y;
        cp[2 * rstride] = v.z;
        cp[3 * rstride] = v.w;
    }
}

// Sum split-K partials: out[i] = alpha * sum_z P[z][i]  (layout-agnostic)
__global__ __launch_bounds__(256) void reduce_k(const float* __restrict__ P,
                                                float* __restrict__ out,
                                                int S, size_t elems, float alpha) {
    size_t idx = ((size_t)blockIdx.x * 256 + threadIdx.x) * 4;
    float4 s = *(const float4*)(P + idx);
    for (int zz = 1; zz < S; ++zz) {
        float4 v = *(const float4*)(P + (size_t)zz * elems + idx);
        s.x += v.x; s.y += v.y; s.z += v.z; s.w += v.w;
    }
    s.x *= alpha; s.y *= alpha; s.z *= alpha; s.w *= alpha;
    *(float4*)(out + idx) = s;
}

// ---------------------------------------------------------------------------
// Middle v3: g-tile 2, grid 1024 (4 blocks/CU). ALL staging up front, ONE
// barrier, no mid-kernel drains. Thread owns channel pair (2p,2p+1) so weights
// come as one ds_read_b64; O1 is (re,im)-interleaved so inc is one ds_read_b64.
__global__ __launch_bounds__(256, 4) void middle_k(const float* __restrict__ O1,
                                                   const unsigned int* __restrict__ wt,
                                                   const float* __restrict__ phi_re,
                                                   const float* __restrict__ phi_im,
                                                   unsigned short* __restrict__ Yt) {
    __shared__ unsigned int sW[2][4096];   // 2 x 16 KB
    __shared__ float sInc[2][1024];        // 2 x 4 KB, interleaved (re,im) per c
    int t = threadIdx.x;
    int g0 = blockIdx.x * 2;
    int b = t >> 5, p = t & 31;

    #pragma unroll
    for (int gt = 0; gt < 2; ++gt) {
        int g = g0 + gt;
        #pragma unroll
        for (int j = 0; j < 4; ++j)
            ASYNC_COPY16(wt + (size_t)g * 4096 + (j * 256 + t) * 4, &sW[gt][(j * 256 + t) * 4]);
        ASYNC_COPY16(O1 + (size_t)g * 1024 + t * 4, &sInc[gt][t * 4]);
    }
    __syncthreads();

    unsigned short reA[2][2], imA[2][2];   // [ch][gt]

    #pragma unroll
    for (int gt = 0; gt < 2; ++gt) {
        int g = g0 + gt;
        float ar0 = 0.f, ai0 = 0.f, ar1 = 0.f, ai1 = 0.f;
        const float2* incp = (const float2*)sInc[gt] + b * 64;
        const unsigned int* wp = sW[gt] + 2 * p;
        #pragma unroll 8
        for (int i = 0; i < 64; ++i) {
            float2 a = incp[i];
            uint2 uu = *(const uint2*)(wp + i * 64);
            float w0r = __uint_as_float(uu.x << 16);
            float w0i = __uint_as_float(uu.x & 0xffff0000u);
            float w1r = __uint_as_float(uu.y << 16);
            float w1i = __uint_as_float(uu.y & 0xffff0000u);
            ar0 += a.x * w0r - a.y * w0i;  ai0 += a.x * w0i + a.y * w0r;
            ar1 += a.x * w1r - a.y * w1i;  ai1 += a.x * w1i + a.y * w1r;
        }
        float pr = phi_re[b * 2048 + g], pi = phi_im[b * 2048 + g];
        reA[0][gt] = f2bf(pr * ar0 - pi * ai0);
        imA[0][gt] = f2bf(pr * ai0 + pi * ar0);
        reA[1][gt] = f2bf(pr * ar1 - pi * ai1);
        imA[1][gt] = f2bf(pr * ai1 + pi * ar1);
    }

    #pragma unroll
    for (int ch = 0; ch < 2; ++ch) {
        int c = 2 * p + ch;
        size_t r0 = (size_t)(b * 64 + c) * 8192;
        size_t rf = (size_t)(b * 64 + 63 - c) * 8192;
        unsigned int ure = (unsigned int)reA[ch][0] | ((unsigned int)reA[ch][1] << 16);
        unsigned int uim = (unsigned int)imA[ch][0] | ((unsigned int)imA[ch][1] << 16);
        *(unsigned int*)(Yt + r0 + g0)        = ure;
        *(unsigned int*)(Yt + r0 + 2048 + g0) = uim;
        *(unsigned int*)(Yt + rf + 4096 + g0) = ure;
        *(unsigned int*)(Yt + rf + 6144 + g0) = uim;
    }
}

// ---------------------------------------------------------------------------
extern "C" void kernel_launch(void* const* d_in, const int* in_sizes, int n_in,
                              void* d_out, int out_size, void* d_ws, size_t ws_size,
                              hipStream_t stream) {
    const float* x     = (const float*)d_in[0];
    const float* emb   = (const float*)d_in[1];
    const float* vf_re = (const float*)d_in[2];
    const float* vf_im = (const float*)d_in[3];
    const float* vi_re = (const float*)d_in[4];
    const float* vi_im = (const float*)d_in[5];
    const float* w1_re = (const float*)d_in[6];
    const float* w1_im = (const float*)d_in[7];
    const float* w2_re = (const float*)d_in[8];
    const float* w2_im = (const float*)d_in[9];
    const float* m1_re = (const float*)d_in[10];
    const float* m1_im = (const float*)d_in[11];
    const float* m2_re = (const float*)d_in[12];
    const float* m2_im = (const float*)d_in[13];

    char* ws = (char*)d_ws;
    unsigned short* Af = (unsigned short*)(ws);                 // 16,777,216
    unsigned short* Xb = (unsigned short*)(ws + 16777216);      //  2,097,152
    unsigned short* Mi = (unsigned short*)(ws + 18874368);      // 33,554,432
    unsigned int*   Wt = (unsigned int*)(ws + 52428800);        // 33,554,432
    float*          O1 = (float*)(ws + 85983232);               //  8,388,608 (interleaved re,im)
    float*       PhiRe = (float*)(ws + 94371840);               //     65,536
    float*       PhiIm = (float*)(ws + 94437376);               //     65,536
    unsigned short* Yt = (unsigned short*)(ws + 94502912);      //  8,388,608
    float*          P  = (float*)(ws + 102891520);              // 33,554,432 partials
    float* out = (float*)d_out;

    pack_all<<<25600, 256, 0, stream>>>(vf_re, vf_im, x, vi_re, vi_im, Af, Xb, Mi);
    pack_wt<<<dim3(16, 64, 2), 256, 0, stream>>>(w1_re, w1_im, w2_re, w2_im, Wt);
    phi_k<<<dim3(2048, 8), 256, 0, stream>>>(m1_re, m1_im, m2_re, m2_im, emb, PhiRe, PhiIm);

    // Forward: interleaved O1 = Af[4096x2048] @ Xb[512x2048]^T, split-K 4
    gemm_sk<<<dim3(4, 32, 4), 256, 0, stream>>>(Af, Xb, P, 4096, 512, 2048, 512, 1);
    reduce_k<<<2048, 256, 0, stream>>>(P, O1, 4, (size_t)4096 * 512, 1.0f);

    middle_k<<<1024, 256, 0, stream>>>(O1, Wt, PhiRe, PhiIm, Yt);

    // Inverse: out[512][2048] = (2/N) * Yt[512x8192] @ Mi[2048x8192]^T, split-K 8
    gemm_sk<<<dim3(16, 4, 8), 256, 0, stream>>>(Yt, Mi, P, 512, 2048, 8192, 1024, 0);
    reduce_k<<<1024, 256, 0, stream>>>(P, out, 8, (size_t)512 * 2048, 1.0f / 1024.0f);
}